// Round 9
// baseline (229.722 us; speedup 1.0000x reference)
//
#include <hip/hip_runtime.h>
#include <hip/hip_bf16.h>

// VectorQuantize: B=4, N=2048, DIM=256, HEADS=4, CODEBOOK=8192, HD=64
// Established (R0-R8): inputs fp32, output fp32 (quantize ++ indices-as-floats).
// Distances fp32-faithful via 3-way bf16 split MFMA (6 terms i+j<=2, rel ~2^-24).
// R5/R8 plateau ~170us: MfmaUtil 51 + VALUBusy 38 -> pipes alternate at
// 2 waves/SIMD; per-stage VALU (~900cyc: split3 staging + 4-op argmin + sv sub)
// equals MFMA issue (~930cyc). R9: (1) codebook pre-split into 3 bf16 planes +
// precomputed -0.5||e||^2 (prep kernel) -> staging VALU gone; (2) acc init
// C=-0.5||e||^2 -> sv sub gone, argmin becomes argmax, 3-op update; (3) dual
// accumulators -> 8-way MFMA ILP (was 4 12-deep chains).

#define HEADS    4
#define CODEBOOK 8192
#define HD       64
#define BQ       8192                  // queries per head = B*N
#define QOFF     (4 * 2048 * 256)      // quantize FLOAT elements in d_out
#define NPART    4
#define CPART    (CODEBOOK / NPART)    // 2048 codes per partition
#define SCODES   64                    // codes per stage
#define NSTAGE   (CPART / SCODES)      // 32 stages

typedef __bf16 bf16x8 __attribute__((ext_vector_type(8)));
typedef float  f32x4  __attribute__((ext_vector_type(4)));

__device__ __bf16 g_p0[HEADS * CODEBOOK * HD];    // split level 0 (4 MB)
__device__ __bf16 g_p1[HEADS * CODEBOOK * HD];    // split level 1
__device__ __bf16 g_p2[HEADS * CODEBOOK * HD];    // split level 2
__device__ float  g_y2n[HEADS * CODEBOOK];        // -0.5*||e||^2 (exact fp32)
__device__ float  g_pval[NPART][HEADS * BQ];      // per-partition best (max acc)
__device__ int    g_pidx[NPART][HEADS * BQ];      // per-partition best index

// split fp32 -> 3 bf16 levels, exact: f == (float)b0 + (float)b1 + (float)b2
__device__ inline void split3(float f, __bf16& b0, __bf16& b1, __bf16& b2) {
    b0 = (__bf16)f;
    float r = f - (float)b0;
    b1 = (__bf16)r;
    r -= (float)b1;
    b2 = (__bf16)r;
}

// ---------------- kernel 0: pre-split codebook + y2 ------------------------
// 262144 threads, one 8-float granule each; width-8 shuffle reduce for y2.
__global__ __launch_bounds__(256) void prep_kernel(const float* __restrict__ embed) {
    int gid = blockIdx.x * 256 + threadIdx.x;     // granule id
    const float* p = embed + (size_t)gid * 8;
    float4 u = *reinterpret_cast<const float4*>(p);
    float4 w = *reinterpret_cast<const float4*>(p + 4);
    float f[8] = {u.x, u.y, u.z, u.w, w.x, w.y, w.z, w.w};
    bf16x8 v0, v1, v2;
    float ss = 0.f;
#pragma unroll
    for (int j = 0; j < 8; j++) {
        __bf16 b0, b1, b2;
        split3(f[j], b0, b1, b2);
        v0[j] = b0; v1[j] = b1; v2[j] = b2;
        ss = fmaf(f[j], f[j], ss);
    }
    *reinterpret_cast<bf16x8*>(g_p0 + (size_t)gid * 8) = v0;
    *reinterpret_cast<bf16x8*>(g_p1 + (size_t)gid * 8) = v1;
    *reinterpret_cast<bf16x8*>(g_p2 + (size_t)gid * 8) = v2;
#pragma unroll
    for (int off = 4; off >= 1; off >>= 1) ss += __shfl_xor(ss, off, 8);
    if ((threadIdx.x & 7) == 0) g_y2n[gid >> 3] = -0.5f * ss;
}

// ---------------- kernel 1: split-bf16 MFMA distances + argmax -------------
// grid = 512 = head(4) x qgroup(32) x part(4); block = 256 (4 waves), 2/CU,
// fully co-resident, zero tail. Each wave owns 64 queries (4 pinned A
// row-tiles); block scans one 2048-code partition in 32 stages of 64 codes
// through double-buffered, XOR-swizzled LDS (conflict-free b128, R5-verified).
// acc initialized to -0.5||e||^2 -> final acc = xy - 0.5||e||^2; argmax(acc)
// == ref argmin of ||x-e||^2 (first-index tie-break via strict >).
// MFMA 16x16x32_bf16 layouts (HW-verified):
//   A: lane -> A[m=lane&15][k=quad*8+j];  B: lane -> B[k=quad*8+j][n=lane&15]
//   C: lane -> col=lane&15, row=quad*4+reg
__global__ __launch_bounds__(256, 2) void dist_kernel(const float* __restrict__ x) {
    __shared__ __align__(16) __bf16 tile[2][3][SCODES * 64];   // 49152 B
    __shared__ float y2s[CPART];                               // 8192 B

    const int bid  = blockIdx.x;
    const int part = bid & 3;
    const int qg   = (bid >> 2) & 31;
    const int h    = bid >> 7;
    const int t    = threadIdx.x;
    const int wave = t >> 6;
    const int lane = t & 63;
    const int col  = lane & 15;
    const int quad = lane >> 4;

    const int qbase = qg * 256 + wave * 64;       // this wave's 64 queries
    const int cbase = part * CPART;

    // A fragments a[rowtile][level][khalf], split on the fly from fp32 x
    bf16x8 a[4][3][2];
#pragma unroll
    for (int rt = 0; rt < 4; rt++) {
#pragma unroll
        for (int kh = 0; kh < 2; kh++) {
            const float* p = x + ((size_t)(qbase + rt * 16 + col) * 256 + h * 64 + kh * 32 + quad * 8);
#pragma unroll
            for (int j = 0; j < 8; j++) {
                __bf16 b0, b1, b2;
                split3(p[j], b0, b1, b2);
                a[rt][0][kh][j] = b0;
                a[rt][1][kh][j] = b1;
                a[rt][2][kh][j] = b2;
            }
        }
    }

    // y2 (negated halves) for this partition -> LDS, 8 floats/thread
    {
        const float* yg = g_y2n + h * CODEBOOK + cbase + t * 8;
        *reinterpret_cast<float4*>(y2s + t * 8)     = *reinterpret_cast<const float4*>(yg);
        *reinterpret_cast<float4*>(y2s + t * 8 + 4) = *reinterpret_cast<const float4*>(yg + 4);
    }

    // staging: thread t owns rows (t>>3), (t>>3)+32, granule t&7; pure copies
    const size_t pbase = ((size_t)h * CODEBOOK + cbase) * HD + (size_t)t * 8;
    const int row  = t >> 3;
    const int gsw  = (t & 7) ^ (row & 7);          // swizzled granule (same for row+32)
    const int ldA  = row * 64 + gsw * 8;           // bf16 units within a level plane
    const int ldB  = (row + 32) * 64 + gsw * 8;

    float bv[4][4]; int bc[4][4];
#pragma unroll
    for (int rt = 0; rt < 4; rt++)
#pragma unroll
        for (int r = 0; r < 4; r++) { bv[rt][r] = -3.4e38f; bc[rt][r] = 0; }

    bf16x8 pf[6];                                  // prefetch: 2 rows x 3 planes

    auto stage_load = [&](int stage) {
        const size_t o = pbase + (size_t)stage * (SCODES * HD);
        pf[0] = *reinterpret_cast<const bf16x8*>(g_p0 + o);
        pf[1] = *reinterpret_cast<const bf16x8*>(g_p1 + o);
        pf[2] = *reinterpret_cast<const bf16x8*>(g_p2 + o);
        pf[3] = *reinterpret_cast<const bf16x8*>(g_p0 + o + 32 * HD);
        pf[4] = *reinterpret_cast<const bf16x8*>(g_p1 + o + 32 * HD);
        pf[5] = *reinterpret_cast<const bf16x8*>(g_p2 + o + 32 * HD);
    };
    auto stage_write = [&](int buf) {
        *reinterpret_cast<bf16x8*>(&tile[buf][0][ldA]) = pf[0];
        *reinterpret_cast<bf16x8*>(&tile[buf][1][ldA]) = pf[1];
        *reinterpret_cast<bf16x8*>(&tile[buf][2][ldA]) = pf[2];
        *reinterpret_cast<bf16x8*>(&tile[buf][0][ldB]) = pf[3];
        *reinterpret_cast<bf16x8*>(&tile[buf][1][ldB]) = pf[4];
        *reinterpret_cast<bf16x8*>(&tile[buf][2][ldB]) = pf[5];
    };

    // preamble: stage 0 staged, stage 1 prefetched, publish
    stage_load(0);
    stage_write(0);
    stage_load(1);
    __syncthreads();

    const int swbase = col & 7;                    // read-side swizzle key

    for (int s = 0; s < NSTAGE; s++) {
        // write stage s+1 into the other buffer, then issue load of stage s+2;
        // the in-flight load drains at THIS stage's end barrier.
        if (s + 1 < NSTAGE) stage_write((s + 1) & 1);
        if (s + 2 < NSTAGE) stage_load(s + 2);

#pragma unroll
        for (int inner = 0; inner < 4; inner++) {
            const int rbase = (inner * 16 + col) * 64;     // row offset in plane
            bf16x8 b[3][2];
#pragma unroll
            for (int lvl = 0; lvl < 3; lvl++)
#pragma unroll
                for (int kh = 0; kh < 2; kh++)
                    b[lvl][kh] = *reinterpret_cast<const bf16x8*>(
                        &tile[s & 1][lvl][rbase + ((((kh << 2) | quad) ^ swbase) << 3)]);

            const int   c   = s * SCODES + inner * 16 + col;   // partition-local code
            const float ycn = y2s[c];                          // -0.5*||e_c||^2
#pragma unroll
            for (int rt = 0; rt < 4; rt++) {
                f32x4 aA = {ycn, ycn, ycn, ycn};               // init-fold
                f32x4 aB = {0.f, 0.f, 0.f, 0.f};
#pragma unroll
                for (int kh = 0; kh < 2; kh++) {               // two 6-chains (8-way ILP w/ rt)
                    aA = __builtin_amdgcn_mfma_f32_16x16x32_bf16(a[rt][0][kh], b[0][kh], aA, 0, 0, 0);
                    aB = __builtin_amdgcn_mfma_f32_16x16x32_bf16(a[rt][0][kh], b[1][kh], aB, 0, 0, 0);
                    aA = __builtin_amdgcn_mfma_f32_16x16x32_bf16(a[rt][1][kh], b[1][kh], aA, 0, 0, 0);
                    aB = __builtin_amdgcn_mfma_f32_16x16x32_bf16(a[rt][1][kh], b[0][kh], aB, 0, 0, 0);
                    aA = __builtin_amdgcn_mfma_f32_16x16x32_bf16(a[rt][0][kh], b[2][kh], aA, 0, 0, 0);
                    aB = __builtin_amdgcn_mfma_f32_16x16x32_bf16(a[rt][2][kh], b[0][kh], aB, 0, 0, 0);
                }
                f32x4 acc = aA + aB;                           // xy - 0.5||e||^2
#pragma unroll
                for (int r = 0; r < 4; r++) {
                    if (acc[r] > bv[rt][r]) { bv[rt][r] = acc[r]; bc[rt][r] = c; }
                }
            }
        }
        __syncthreads();
    }

    // reduce across 16 column slots; lexicographic (max val, min idx) =
    // np first-argmax tie-break
#pragma unroll
    for (int rt = 0; rt < 4; rt++) {
#pragma unroll
        for (int r = 0; r < 4; r++) {
            float v = bv[rt][r]; int c = bc[rt][r];
#pragma unroll
            for (int off = 8; off >= 1; off >>= 1) {
                float ov = __shfl_xor(v, off, 16); int oc = __shfl_xor(c, off, 16);
                if (ov > v || (ov == v && oc < c)) { v = ov; c = oc; }
            }
            if (col == 0) {
                int q = h * BQ + qbase + rt * 16 + quad * 4 + r;
                g_pval[part][q] = v; g_pidx[part][q] = cbase + c;
            }
        }
    }
}

// ---------------- kernel 2: merge partitions + gather + index write --------
__global__ __launch_bounds__(256) void merge_kernel(const float* __restrict__ embed,
                                                    float* __restrict__ out) {
    int id = blockIdx.x * 256 + threadIdx.x;   // m*4 + h  (m-major, coalesced idx write)
    int m = id >> 2;
    int h = id & 3;
    int q = h * BQ + m;

    float bv = g_pval[0][q]; int bc = g_pidx[0][q];
#pragma unroll
    for (int p = 1; p < NPART; p++) {
        float v = g_pval[p][q]; int c = g_pidx[p][q];
        if (v > bv || (v == bv && c < bc)) { bv = v; bc = c; }
    }

    out[QOFF + id] = (float)bc;                // embed_ind[b][n][h] as fp32 value

    int idx = bc & (CODEBOOK - 1);             // defensive in-range
    const float* src = embed + ((size_t)h * CODEBOOK + idx) * HD;
    float*       dst = out + (size_t)m * 256 + h * 64;
#pragma unroll
    for (int i = 0; i < 16; i++)               // 64 fp32, verbatim
        *reinterpret_cast<float4*>(dst + i * 4) = *reinterpret_cast<const float4*>(src + i * 4);
}

extern "C" void kernel_launch(void* const* d_in, const int* in_sizes, int n_in,
                              void* d_out, int out_size, void* d_ws, size_t ws_size,
                              hipStream_t stream) {
    const float* x     = (const float*)d_in[0];
    const float* embed = (const float*)d_in[1];
    float*       out   = (float*)d_out;

    prep_kernel <<<1024, 256, 0, stream>>>(embed);
    dist_kernel <<<512,  256, 0, stream>>>(x);
    merge_kernel<<<128,  256, 0, stream>>>(embed, out);
}

// Round 10
// 189.530 us; speedup vs baseline: 1.2121x; 1.2121x over previous
//
#include <hip/hip_runtime.h>
#include <hip/hip_bf16.h>

// VectorQuantize: B=4, N=2048, DIM=256, HEADS=4, CODEBOOK=8192, HD=64
// Established (R0-R9): inputs fp32, output fp32 (quantize ++ indices-as-floats).
// R8: bf16 3-level split (6 MFMA terms), 174.7us dist, MfmaUtil 51. MFMA issue
// floor for 6 terms = 99us -> 58% util; ~42% exposed overhead at 2 waves/SIMD.
// R9 (pre-split global planes): neutral dist, worse total (locality + cold prep).
// R10: (a) fp16 2-LEVEL split -> 3 MFMA terms, same 2^-24 error class:
//   x = x0 + x1/4096 + dx, x0=fp16(x), x1=fp16(4096*(x-x0)), |dx|<=2^-24|x|.
//   accA = sum x0*e0 - 0.5||e||^2 (init-fold);  accB = sum x0*e1 + x1*e0;
//   score = accA + 2^-12*accB  (dropped x1*e1/4096^2 ~ 2^-24).
//   MFMA floor halves: 99 -> 50us. LDS: 2 planes, block 36.9KB.
// (b) NPART=8 -> grid 1024 -> 3-4 blocks/CU (fits now: LDS 4x36.9=147K<160K),
//   filling the exposed-overhead fraction with other waves' MFMA. R7's failure
//   causes (serial y2 preamble, pre-split FETCH blowup) are absent here.

#define HEADS    4
#define CODEBOOK 8192
#define HD       64
#define BQ       8192                  // queries per head = B*N
#define QOFF     (4 * 2048 * 256)      // quantize FLOAT elements in d_out
#define NPART    8
#define CPART    (CODEBOOK / NPART)    // 1024 codes per partition
#define SCODES   64                    // codes per stage
#define NSTAGE   (CPART / SCODES)      // 16 stages
#define RSCALE   4096.0f               // residual scale (2^12)
#define RINV     (1.0f / 4096.0f)

typedef _Float16 f16x8 __attribute__((ext_vector_type(8)));
typedef float    f32x4 __attribute__((ext_vector_type(4)));

__device__ float g_pval[NPART][HEADS * BQ];       // per-partition best (max score)
__device__ int   g_pidx[NPART][HEADS * BQ];       // per-partition best index

// split fp32 -> 2 fp16 levels: f ~= (float)h0 + (float)h1 / 4096, |err|<=2^-24|f|
__device__ inline void split2(float f, _Float16& h0, _Float16& h1) {
    h0 = (_Float16)f;
    float r = f - (float)h0;
    h1 = (_Float16)(r * RSCALE);
}

// ---------------- kernel 1: split-fp16 MFMA scores + argmax ----------------
// grid = 1024 = head(4) x qgroup(32) x part(8); block = 256 (4 waves).
// Each wave owns 64 queries (4 pinned A row-tiles); block scans one 1024-code
// partition in 16 stages of 64 codes through double-buffered, XOR-swizzled LDS
// (conflict-free b128 write+read — verified R5/R8: SQ_LDS_BANK_CONFLICT == 0).
// y2 (= -0.5||e||^2) computed for free inside the staging path (R8-verified).
// MFMA 16x16x32_f16 layouts (same operand shape as bf16, HW-verified family):
//   A: lane -> A[m=lane&15][k=quad*8+j];  B: lane -> B[k=quad*8+j][n=lane&15]
//   C: lane -> col=lane&15, row=quad*4+reg
__global__ __launch_bounds__(256, 2) void dist_kernel(const float* __restrict__ x,
                                                      const float* __restrict__ embed) {
    __shared__ __align__(16) _Float16 tile[2][2][SCODES * 64];   // 32768 B
    __shared__ float y2s[CPART];                                 // 4096 B

    const int bid  = blockIdx.x;
    const int part = bid & 7;
    const int qg   = (bid >> 3) & 31;
    const int h    = bid >> 8;
    const int t    = threadIdx.x;
    const int wave = t >> 6;
    const int lane = t & 63;
    const int col  = lane & 15;
    const int quad = lane >> 4;

    const int qbase = qg * 256 + wave * 64;       // this wave's 64 queries
    const int cbase = part * CPART;

    // A fragments a[rowtile][level][khalf], split on the fly from fp32 x
    f16x8 a[4][2][2];
#pragma unroll
    for (int rt = 0; rt < 4; rt++) {
#pragma unroll
        for (int kh = 0; kh < 2; kh++) {
            const float* p = x + ((size_t)(qbase + rt * 16 + col) * 256 + h * 64 + kh * 32 + quad * 8);
#pragma unroll
            for (int j = 0; j < 8; j++) {
                _Float16 h0, h1;
                split2(p[j], h0, h1);
                a[rt][0][kh][j] = h0;
                a[rt][1][kh][j] = h1;
            }
        }
    }

    // staging: thread t owns rows (t>>3), (t>>3)+32, 8-float granule t&7
    const float* esrc = embed + ((size_t)h * CODEBOOK + cbase) * HD + (size_t)t * 8;
    const int row  = t >> 3;
    const int gsw  = (t & 7) ^ (row & 7);          // swizzled granule (same for row+32)
    const int ldA  = row * 64 + gsw * 8;           // f16 units within a level plane
    const int ldB  = (row + 32) * 64 + gsw * 8;

    float bv[4][4]; int bc[4][4];
#pragma unroll
    for (int rt = 0; rt < 4; rt++)
#pragma unroll
        for (int r = 0; r < 4; r++) { bv[rt][r] = -3.4e38f; bc[rt][r] = 0; }

    float4 pfA0, pfA1, pfB0, pfB1;                 // prefetch regs (2 rows x 8 floats)

    // split both rows -> 2 LDS planes of `buf`; also compute + publish -0.5*y2
    auto stage_write = [&](int buf, int stage) {
        float fA[8] = {pfA0.x, pfA0.y, pfA0.z, pfA0.w, pfA1.x, pfA1.y, pfA1.z, pfA1.w};
        float fB[8] = {pfB0.x, pfB0.y, pfB0.z, pfB0.w, pfB1.x, pfB1.y, pfB1.z, pfB1.w};
        f16x8 vA0, vA1, vB0, vB1;
        float ssA = 0.f, ssB = 0.f;
#pragma unroll
        for (int j = 0; j < 8; j++) {
            _Float16 h0, h1;
            split2(fA[j], h0, h1);
            vA0[j] = h0; vA1[j] = h1;
            ssA = fmaf(fA[j], fA[j], ssA);
            split2(fB[j], h0, h1);
            vB0[j] = h0; vB1[j] = h1;
            ssB = fmaf(fB[j], fB[j], ssB);
        }
        *reinterpret_cast<f16x8*>(&tile[buf][0][ldA]) = vA0;
        *reinterpret_cast<f16x8*>(&tile[buf][1][ldA]) = vA1;
        *reinterpret_cast<f16x8*>(&tile[buf][0][ldB]) = vB0;
        *reinterpret_cast<f16x8*>(&tile[buf][1][ldB]) = vB1;
#pragma unroll
        for (int off = 4; off >= 1; off >>= 1) {   // width-8 granule tree
            ssA += __shfl_xor(ssA, off, 8);
            ssB += __shfl_xor(ssB, off, 8);
        }
        if ((t & 7) == 0) {
            y2s[stage * SCODES + row]      = -0.5f * ssA;
            y2s[stage * SCODES + row + 32] = -0.5f * ssB;
        }
    };
    auto stage_load = [&](int stage) {
        const float* ps = esrc + (size_t)stage * (SCODES * HD);
        pfA0 = *reinterpret_cast<const float4*>(ps);
        pfA1 = *reinterpret_cast<const float4*>(ps + 4);
        pfB0 = *reinterpret_cast<const float4*>(ps + 32 * HD);
        pfB1 = *reinterpret_cast<const float4*>(ps + 32 * HD + 4);
    };

    // preamble: stage 0 staged + y2, stage 1 prefetched, publish
    stage_load(0);
    stage_write(0, 0);
    stage_load(1);
    __syncthreads();

    const int swbase = col & 7;                    // read-side swizzle key

    for (int s = 0; s < NSTAGE; s++) {
        // write stage s+1 (+ its y2) into the other buffer, then issue load of
        // stage s+2; the in-flight load drains at THIS stage's end barrier.
        if (s + 1 < NSTAGE) stage_write((s + 1) & 1, s + 1);
        if (s + 2 < NSTAGE) stage_load(s + 2);

#pragma unroll
        for (int inner = 0; inner < 4; inner++) {
            const int rbase = (inner * 16 + col) * 64;     // row offset in plane
            f16x8 b[2][2];
#pragma unroll
            for (int lvl = 0; lvl < 2; lvl++)
#pragma unroll
                for (int kh = 0; kh < 2; kh++)
                    b[lvl][kh] = *reinterpret_cast<const f16x8*>(
                        &tile[s & 1][lvl][rbase + ((((kh << 2) | quad) ^ swbase) << 3)]);

            const int   c   = s * SCODES + inner * 16 + col;   // partition-local code
            const float ycn = y2s[c];                          // -0.5*||e_c||^2
#pragma unroll
            for (int rt = 0; rt < 4; rt++) {
                f32x4 aA = {ycn, ycn, ycn, ycn};               // init-fold of -0.5||e||^2
                f32x4 aB = {0.f, 0.f, 0.f, 0.f};
#pragma unroll
                for (int kh = 0; kh < 2; kh++) {               // 3 terms x 2 kh; 8-way ILP w/ rt
                    aA = __builtin_amdgcn_mfma_f32_16x16x32_f16(a[rt][0][kh], b[0][kh], aA, 0, 0, 0);
                    aB = __builtin_amdgcn_mfma_f32_16x16x32_f16(a[rt][0][kh], b[1][kh], aB, 0, 0, 0);
                    aB = __builtin_amdgcn_mfma_f32_16x16x32_f16(a[rt][1][kh], b[0][kh], aB, 0, 0, 0);
                }
#pragma unroll
                for (int r = 0; r < 4; r++) {
                    float sv = fmaf(aB[r], RINV, aA[r]);       // xy - 0.5||e||^2
                    if (sv > bv[rt][r]) { bv[rt][r] = sv; bc[rt][r] = c; }
                }
            }
        }
        __syncthreads();
    }

    // reduce across 16 column slots; lexicographic (max val, min idx) =
    // np first-argmax tie-break
#pragma unroll
    for (int rt = 0; rt < 4; rt++) {
#pragma unroll
        for (int r = 0; r < 4; r++) {
            float v = bv[rt][r]; int c = bc[rt][r];
#pragma unroll
            for (int off = 8; off >= 1; off >>= 1) {
                float ov = __shfl_xor(v, off, 16); int oc = __shfl_xor(c, off, 16);
                if (ov > v || (ov == v && oc < c)) { v = ov; c = oc; }
            }
            if (col == 0) {
                int q = h * BQ + qbase + rt * 16 + quad * 4 + r;
                g_pval[part][q] = v; g_pidx[part][q] = cbase + c;
            }
        }
    }
}

// ---------------- kernel 2: merge partitions + gather + index write --------
__global__ __launch_bounds__(256) void merge_kernel(const float* __restrict__ embed,
                                                    float* __restrict__ out) {
    int id = blockIdx.x * 256 + threadIdx.x;   // m*4 + h  (m-major, coalesced idx write)
    int m = id >> 2;
    int h = id & 3;
    int q = h * BQ + m;

    float bv = g_pval[0][q]; int bc = g_pidx[0][q];
#pragma unroll
    for (int p = 1; p < NPART; p++) {
        float v = g_pval[p][q]; int c = g_pidx[p][q];
        if (v > bv || (v == bv && c < bc)) { bv = v; bc = c; }
    }

    out[QOFF + id] = (float)bc;                // embed_ind[b][n][h] as fp32 value

    int idx = bc & (CODEBOOK - 1);             // defensive in-range
    const float* src = embed + ((size_t)h * CODEBOOK + idx) * HD;
    float*       dst = out + (size_t)m * 256 + h * 64;
#pragma unroll
    for (int i = 0; i < 16; i++)               // 64 fp32, verbatim
        *reinterpret_cast<float4*>(dst + i * 4) = *reinterpret_cast<const float4*>(src + i * 4);
}

extern "C" void kernel_launch(void* const* d_in, const int* in_sizes, int n_in,
                              void* d_out, int out_size, void* d_ws, size_t ws_size,
                              hipStream_t stream) {
    const float* x     = (const float*)d_in[0];
    const float* embed = (const float*)d_in[1];
    float*       out   = (float*)d_out;

    dist_kernel <<<1024, 256, 0, stream>>>(x, embed);
    merge_kernel<<<128,  256, 0, stream>>>(embed, out);
}